// Round 7
// baseline (129.902 us; speedup 1.0000x reference)
//
#include <hip/hip_runtime.h>
#include <hip/hip_bf16.h>
#include <math.h>

// NT-Xent loss, fused flash-style. N=8192 rows, D=256.
//   k_norm: row L2-normalize fp32 -> bf16 (ws); zero sumexp + out
//   k_sim : bf16 MFMA, exp((sim-1)/T) in-register, row+col sums via symmetry
//   k_nll : exact fp32 pos dot + per-row nll + mean via atomicAdd
//
// History:
//   R1: 64x64 wave tile @ (256,2): ~280 demand -> spill, 77 us.
//   R2: 32x64 tile @ (256,3): budget 168 < ~230 demand -> spill, 82 us.
//   R3: 32x64 tile @ (256,2): no spill, k_sim 49.3 us.
//   R4: LDS double-buffer w/ vmcnt(0) drains: REGRESSED (57).
//   R5: 64 rows/wave (halved LDS reads): -2 only (47.2).
//   R6: symmetry (row sums == col sums): 42.3. R7: strip balance: null.
//   R8: B direct-from-global: REGRESSED (59). R9: counted-vmcnt 2-deep
//       double buffer: NULL (41). => stall is NOT DMA-wait, NOT LDS
//       traffic, NOT tail, NOT barrier drains. Remaining candidate:
//       per-SIMD dependency bubbles at only 2 waves/SIMD (every variant
//       kept afrag=128 VGPR -> (256,2)). m97-class GEMMs need 3 waves/SIMD.
//   R10 (this): buy the 3rd wave/SIMD. 32 rows/wave -> afrag 64, acc 16,
//       total ~140 < 168 @ (256,3). 128x128 tiles (2080 upper-tri), 32-col
//       strips (8320), grid 768 = exactly 3 blocks/CU, LDS 96 KB/CU.
//       Keep: symmetry+csum, swizzled STAGE, counted vmcnt (steady 6 /
//       post-boundary 30 / prologue 20; queue kept composition-invariant
//       via diag dummy-atomics + always-stage tail), setprio on MFMA.
#define N_ROWS 8192
#define D_DIM  256
#define HALF_N 4096
#define INV_T      14.285714285714286f      // 1/0.07
#define SCALE_LOG2 20.609929155556620f      // log2(e)/0.07
#define NEG_SCALE  -20.609929155556620f
#define EPSV   1e-8f

typedef __attribute__((ext_vector_type(8))) short bf16x8;   // 8 bf16 = 4 VGPR
typedef __attribute__((ext_vector_type(4))) float f32x4;

#define AS1 __attribute__((address_space(1)))
#define AS3 __attribute__((address_space(3)))

__device__ inline unsigned short f2bf(float x) {
    unsigned int u = __float_as_uint(x);
    unsigned int r = (u + 0x7fffu + ((u >> 16) & 1u)) >> 16;   // RNE
    return (unsigned short)r;
}

// ---------------- kernel 1: normalize rows, emit bf16; zero accumulators ---
__global__ __launch_bounds__(256) void k_norm(const float* __restrict__ feat,
                                              unsigned short* __restrict__ fbf,
                                              float* __restrict__ sumexp,
                                              float* __restrict__ out) {
    const int tid = threadIdx.x;
    const int gid = blockIdx.x * 256 + tid;
    if (gid < N_ROWS) sumexp[gid] = 0.f;
    if (gid == 0) out[0] = 0.f;

    const int w = tid >> 6, lane = tid & 63;
    const int row = blockIdx.x * 4 + w;              // 2048 blocks * 4 rows
    const float4 v = ((const float4*)(feat + row * D_DIM))[lane];
    float ss = v.x*v.x + v.y*v.y + v.z*v.z + v.w*v.w;
    #pragma unroll
    for (int off = 32; off; off >>= 1) ss += __shfl_xor(ss, off);
    const float scale = 1.f / fmaxf(sqrtf(ss), EPSV);
    ushort4 o;
    o.x = f2bf(v.x * scale);
    o.y = f2bf(v.y * scale);
    o.z = f2bf(v.z * scale);
    o.w = f2bf(v.w * scale);
    ((ushort4*)(fbf + row * D_DIM))[lane] = o;
}

// ---------------- kernel 2: fused sim + exp + row/col-sum (symmetric) ------
// Work unit = strip (tile tt, jt): 128 rows x 32 cols, tt over the 2080
// upper-triangle 128x128 tiles (rt >= cs), jt in [0,4). 8320 strips total,
// block b owns strips [(65b)/6, (65(b+1))/6) (10 or 11). 4 waves x 32 rows;
// A (32x256) in regs (64 VGPR). B strip = 16 KB LDS via global_load_lds
// w=16, XOR-16B-chunk swizzle (conflict-free ds_read_b128). 2-deep double
// buffer with counted vmcnt; vmem queue kept composition-invariant:
//   steady top-of-iter:      newer-than-STAGE(g) = STAGE(g+1)[4]+csum[2]=6
//   after a tile boundary:   + FLUSH[8] + LOAD_A[16]            = 30
//   first iteration:         STAGE(g+1)[4] + LOAD_A[16]         = 20
// Diag strips issue 2 dummy atomics; the tail always stages (clamped walk
// stays inside the mapped workspace) so these counts hold on every path.
__global__ __launch_bounds__(256, 3) void k_sim(const unsigned short* __restrict__ fbf,
                                                float* __restrict__ sumexp) {
    __shared__ __align__(16) char Bs[32768];       // 2 x 16 KB
    const int tid  = threadIdx.x;
    const int lane = tid & 63;
    const int w    = tid >> 6;
    const int q    = lane >> 4, l15 = lane & 15;

    int g          = (65 * blockIdx.x) / 6;           // first strip
    const int gEnd = (65 * (blockIdx.x + 1)) / 6;     // one past last

    // decode tile of strip g: tt -> (rt, cs), rt >= cs (64 row-tiles of 128)
    const int tt0 = g >> 2;
    int rt = (int)((sqrtf(8.f * (float)tt0 + 1.f) - 1.f) * 0.5f);
    while ((rt + 1) * (rt + 2) / 2 <= tt0) ++rt;
    while (rt * (rt + 1) / 2 > tt0) --rt;
    int cs = tt0 - rt * (rt + 1) / 2;
    int jt = g & 3;

#define ADV(rt_, cs_, jt_) do {                                               \
        if (++jt_ == 4) { jt_ = 0; if (++cs_ > rt_) { cs_ = 0; ++rt_; } }     \
    } while (0)

    int nrt = rt, ncs = cs, njt = jt;                 // coords of strip g+1
    ADV(nrt, ncs, njt);

#define STAGE(colRow0, par) do {                                              \
        const char* Bg_ = (const char*)fbf + (size_t)(colRow0) * 512;         \
        char* Bd_ = Bs + ((par) << 14);                                       \
        _Pragma("unroll")                                                     \
        for (int i_ = 0; i_ < 4; ++i_) {                                      \
            const int idx_ = i_ * 256 + tid;                                  \
            const int col_ = idx_ >> 5;                                       \
            const int cir_ = idx_ & 31;                                       \
            __builtin_amdgcn_global_load_lds(                                 \
                (const AS1 void*)(Bg_ + col_ * 512 + ((cir_ ^ (col_ & 7)) << 4)), \
                (AS3 void*)(Bd_ + idx_ * 16), 16, 0, 0);                      \
        }                                                                     \
    } while (0)

    bf16x8 afrag[8][2];                               // 32 rows x 256 k
#define LOAD_A(rt_) do {                                                      \
        const int rowBase_ = (rt_) * 128 + w * 32;                            \
        _Pragma("unroll")                                                     \
        for (int t_ = 0; t_ < 8; ++t_)                                        \
            _Pragma("unroll")                                                 \
            for (int ri_ = 0; ri_ < 2; ++ri_)                                 \
                afrag[t_][ri_] = *(const bf16x8*)(fbf                         \
                    + (rowBase_ + ri_*16 + l15) * D_DIM + t_*32 + q*8);       \
    } while (0)

    float rsum[2][4];
#define ZERO_RSUM() do {                                                      \
        _Pragma("unroll")                                                     \
        for (int ri_ = 0; ri_ < 2; ++ri_)                                     \
            _Pragma("unroll")                                                 \
            for (int r_ = 0; r_ < 4; ++r_) rsum[ri_][r_] = 0.f;               \
    } while (0)

    // 8 atomic instrs per flush (2 ri x 4 r)
#define FLUSH_RSUM(rt_) do {                                                  \
        const int rowBase_ = (rt_) * 128 + w * 32;                            \
        _Pragma("unroll")                                                     \
        for (int ri_ = 0; ri_ < 2; ++ri_)                                     \
            _Pragma("unroll")                                                 \
            for (int r_ = 0; r_ < 4; ++r_) {                                  \
                float s_ = rsum[ri_][r_];                                     \
                s_ += __shfl_xor(s_, 1);                                      \
                s_ += __shfl_xor(s_, 2);                                      \
                s_ += __shfl_xor(s_, 4);                                      \
                s_ += __shfl_xor(s_, 8);                                      \
                if (l15 == 0)                                                 \
                    atomicAdd(&sumexp[rowBase_ + ri_ * 16 + q * 4 + r_], s_); \
            }                                                                 \
    } while (0)

    // prologue: stage strips g and g+1, load A for tile of g
    STAGE(cs * 128 + jt * 32, 0);
    STAGE(ncs * 128 + njt * 32, 1);
    LOAD_A(rt);
    ZERO_RSUM();

    int p = 0;
    bool first = true, postBoundary = false;
    while (true) {
        const int colBase = cs * 128 + jt * 32;
        const bool isDiag = (rt == cs);
        const int rowBase = rt * 128 + w * 32;

        // counted wait for STAGE(g): allow exactly the vmem ops issued
        // after it (see header). Never drains the in-flight prefetch.
        if (first)             { asm volatile("s_waitcnt vmcnt(20)" ::: "memory"); first = false; }
        else if (postBoundary) { asm volatile("s_waitcnt vmcnt(30)" ::: "memory"); postBoundary = false; }
        else                   { asm volatile("s_waitcnt vmcnt(6)"  ::: "memory"); }
        __builtin_amdgcn_s_barrier();                 // buf[p] ready for all
        __builtin_amdgcn_sched_barrier(0);            // no ds_read hoist up

        const char* Bp = Bs + (p << 14);

        f32x4 acc[2][2];
        #pragma unroll
        for (int ri = 0; ri < 2; ++ri)
            #pragma unroll
            for (int ci = 0; ci < 2; ++ci) acc[ri][ci] = (f32x4){0.f, 0.f, 0.f, 0.f};

        __builtin_amdgcn_s_setprio(1);
        #pragma unroll
        for (int t = 0; t < 8; ++t) {
            bf16x8 bfrag[2];
            #pragma unroll
            for (int ci = 0; ci < 2; ++ci) {
                const int c   = ci * 16 + l15;     // local col 0..31
                const int cir = t * 4 + q;         // k-chunk
                bfrag[ci] = *(const bf16x8*)(Bp + c * 512 + ((cir ^ (c & 7)) << 4));
            }
            #pragma unroll
            for (int ri = 0; ri < 2; ++ri)
                #pragma unroll
                for (int ci = 0; ci < 2; ++ci)
                    acc[ri][ci] = __builtin_amdgcn_mfma_f32_16x16x32_bf16(
                        afrag[t][ri], bfrag[ci], acc[ri][ci], 0, 0, 0);
        }
        __builtin_amdgcn_s_setprio(0);

        __builtin_amdgcn_sched_barrier(0);            // pin reads above bar
        __builtin_amdgcn_s_barrier();                 // all done reading buf[p]

        // ALWAYS stage (g+2 or a clamped dummy) so the vmem queue keeps its
        // invariant shape; a full strip period of latency lead.
        const bool more = (g + 1 < gEnd);
        int rt2 = nrt, cs2 = ncs, jt2 = njt;
        ADV(rt2, cs2, jt2);                           // coords of strip g+2
        STAGE(cs2 * 128 + jt2 * 32, p);               // dummy reads stay in ws

        // epilogue: e = exp2(acc*S - S). C/D layout: col=l15, row=q*4+reg.
        if (isDiag) {
            #pragma unroll
            for (int ri = 0; ri < 2; ++ri) {
                const int trow = rowBase + ri * 16;
                #pragma unroll
                for (int ci = 0; ci < 2; ++ci) {
                    const int tcol = colBase + ci * 16;
                    if (trow == tcol) {            // diagonal 16x16 tile
                        #pragma unroll
                        for (int r = 0; r < 4; ++r) {
                            const float e = __builtin_amdgcn_exp2f(
                                __builtin_fmaf(acc[ri][ci][r], SCALE_LOG2, NEG_SCALE));
                            rsum[ri][r] += (q * 4 + r == l15) ? 0.f : e;
                        }
                    } else {
                        #pragma unroll
                        for (int r = 0; r < 4; ++r)
                            rsum[ri][r] += __builtin_amdgcn_exp2f(
                                __builtin_fmaf(acc[ri][ci][r], SCALE_LOG2, NEG_SCALE));
                    }
                }
            }
            // dummy atomics: keep vmem-queue composition invariant
            if (q == 0)      atomicAdd(&sumexp[colBase      + l15], 0.f);
            else if (q == 1) atomicAdd(&sumexp[colBase + 16 + l15], 0.f);
        } else {
            // off-diagonal (rt > cs): rsum for rows AND csum for cols
            float csum0 = 0.f, csum1 = 0.f;
            #pragma unroll
            for (int ri = 0; ri < 2; ++ri) {
                #pragma unroll
                for (int r = 0; r < 4; ++r) {
                    const float e0 = __builtin_amdgcn_exp2f(
                        __builtin_fmaf(acc[ri][0][r], SCALE_LOG2, NEG_SCALE));
                    const float e1 = __builtin_amdgcn_exp2f(
                        __builtin_fmaf(acc[ri][1][r], SCALE_LOG2, NEG_SCALE));
                    rsum[ri][r] += e0 + e1;
                    csum0 += e0;
                    csum1 += e1;
                }
            }
            // reduce csum over the 4 q-groups (wave rows live across q)
            csum0 += __shfl_xor(csum0, 16); csum0 += __shfl_xor(csum0, 32);
            csum1 += __shfl_xor(csum1, 16); csum1 += __shfl_xor(csum1, 32);
            if (q == 0)      atomicAdd(&sumexp[colBase      + l15], csum0);
            else if (q == 1) atomicAdd(&sumexp[colBase + 16 + l15], csum1);
        }

        if (!more) break;
        // boundary: flush AFTER this strip's epilogue, then reload A; the
        // next top-of-iter wait accounts for these via vmcnt(30).
        if (njt == 0) {
            FLUSH_RSUM(rt);
            LOAD_A(nrt);
            ZERO_RSUM();
            postBoundary = true;
        }
        rt = nrt; cs = ncs; jt = njt;
        nrt = rt2; ncs = cs2; njt = jt2;
        p ^= 1; ++g;
    }

    FLUSH_RSUM(rt);
#undef ADV
#undef STAGE
#undef LOAD_A
#undef ZERO_RSUM
#undef FLUSH_RSUM
}

// ---------------- kernel 3: exact pos similarity + nll + mean --------------
__global__ __launch_bounds__(256) void k_nll(const float* __restrict__ feat,
                                             const float* __restrict__ sumexp,
                                             float* __restrict__ out) {
    __shared__ float red[4];
    const int tid = threadIdx.x, w = tid >> 6, lane = tid & 63;
    const int i  = blockIdx.x * 4 + w;
    const int pc = (i + HALF_N) & (N_ROWS - 1);
    const float4 a = ((const float4*)(feat + i  * D_DIM))[lane];
    const float4 b = ((const float4*)(feat + pc * D_DIM))[lane];
    float dab = a.x*b.x + a.y*b.y + a.z*b.z + a.w*b.w;
    float daa = a.x*a.x + a.y*a.y + a.z*a.z + a.w*a.w;
    float dbb = b.x*b.x + b.y*b.y + b.z*b.z + b.w*b.w;
    #pragma unroll
    for (int off = 32; off; off >>= 1) {
        dab += __shfl_xor(dab, off);
        daa += __shfl_xor(daa, off);
        dbb += __shfl_xor(dbb, off);
    }
    if (lane == 0) {
        const float pos = dab / (fmaxf(sqrtf(daa), EPSV) * fmaxf(sqrtf(dbb), EPSV));
        red[w] = INV_T + logf(sumexp[i]) - pos * INV_T;
    }
    __syncthreads();
    if (tid == 0)
        atomicAdd(out, (red[0] + red[1] + red[2] + red[3]) * (1.f / N_ROWS));
}

extern "C" void kernel_launch(void* const* d_in, const int* in_sizes, int n_in,
                              void* d_out, int out_size, void* d_ws, size_t ws_size,
                              hipStream_t stream) {
    const float* feat = (const float*)d_in[0];
    char* ws = (char*)d_ws;
    unsigned short* fbf = (unsigned short*)ws;                 // 4 MB bf16
    float* sumexp = (float*)(ws + 4u * 1024u * 1024u);         // 32 KB

    k_norm<<<N_ROWS / 4, 256, 0, stream>>>(feat, fbf, sumexp, (float*)d_out);
    k_sim <<<768,        256, 0, stream>>>(fbf, sumexp);
    k_nll <<<N_ROWS / 4, 256, 0, stream>>>(feat, sumexp, (float*)d_out);
}